// Round 1
// baseline (368.936 us; speedup 1.0000x reference)
//
#include <hip/hip_runtime.h>
#include <hip/hip_bf16.h>
#include <stdint.h>

// GatheringLoss: score = q[32768x512] @ items[4096x512]^T, idx = argmax_row,
// out = mean((q - items[idx])^2).
// Phase 1: cast q,items fp32->fp16 into ws.
// Phase 2: MFMA score kernel (m97-style 128x128 tile, BK=64) with per-lane
//          running (max,argmax); fused exact-fp32 loss; per-block partial.
// Phase 3: reduce 256 partials -> scalar.
//
// ws layout: [0, 32MB) q_fp16 | [32MB, 36MB) items_fp16 | [36MB, +1KB) partials

#define D_DIM 512
#define M_ITEMS 4096
#define N_ROWS 32768
#define BM 128
#define BN 128
#define BK 64
#define N_CT (M_ITEMS / BN) // 32
#define N_KS (D_DIM / BK)   // 8

typedef _Float16 half8 __attribute__((ext_vector_type(8)));
typedef _Float16 half4h __attribute__((ext_vector_type(4)));
typedef float f32x4 __attribute__((ext_vector_type(4)));

#define GLD_LDS16(g, l)                                                        \
  __builtin_amdgcn_global_load_lds(                                            \
      (__attribute__((address_space(1))) const void*)(g),                      \
      (__attribute__((address_space(3))) void*)(l), 16, 0, 0)

__global__ __launch_bounds__(256) void cast_f32_f16(
    const float* __restrict__ in, _Float16* __restrict__ out, int n4) {
  const int stride = gridDim.x * blockDim.x;
  for (int i = blockIdx.x * blockDim.x + threadIdx.x; i < n4; i += stride) {
    const float4 v = reinterpret_cast<const float4*>(in)[i];
    half4h h;
    h.x = (_Float16)v.x;
    h.y = (_Float16)v.y;
    h.z = (_Float16)v.z;
    h.w = (_Float16)v.w;
    reinterpret_cast<half4h*>(out)[i] = h;
  }
}

__global__ __launch_bounds__(256) void gather_loss_main(
    const float* __restrict__ qf, const float* __restrict__ itf,
    const _Float16* __restrict__ qh, const _Float16* __restrict__ ih,
    float* __restrict__ partials) {
  __shared__ _Float16 Ah[BM * BK]; // [row][k] linear (global_load_lds dest)
  __shared__ _Float16 Bh[BN * BK]; // [col][k] linear
  __shared__ float sVal[2][BM];
  __shared__ int sIdx[2][BM];
  __shared__ float sSum[4];

  const int t = threadIdx.x;
  const int lane = t & 63;
  const int wv = t >> 6;  // 0..3
  const int wr = wv >> 1; // row half 0..1
  const int wc = wv & 1;  // col half 0..1
  const int ln = lane & 15;
  const int lg = lane >> 4; // 0..3
  const int row0 = blockIdx.x * BM;

  // per-lane running max over the columns this lane sees
  float rmax[4][4];
  int ridx[4][4];
#pragma unroll
  for (int a = 0; a < 4; ++a)
#pragma unroll
    for (int b = 0; b < 4; ++b) {
      rmax[a][b] = -3.0e38f;
      ridx[a][b] = 0;
    }

  for (int ct = 0; ct < N_CT; ++ct) {
    const int col0 = ct * BN;
    f32x4 acc[4][4];
#pragma unroll
    for (int a = 0; a < 4; ++a)
#pragma unroll
      for (int b = 0; b < 4; ++b)
#pragma unroll
        for (int r = 0; r < 4; ++r) acc[a][b][r] = 0.0f;

    for (int ks = 0; ks < N_KS; ++ks) {
      __syncthreads(); // protect LDS from previous readers
      // stage A tile (128x64 fp16 = 16KB): 4 x 16B per thread
#pragma unroll
      for (int i = 0; i < 4; ++i) {
        const int flat = i * 2048 + t * 8; // element index in tile
        const int r = flat >> 6;
        const int c = flat & 63;
        GLD_LDS16(qh + (size_t)(row0 + r) * D_DIM + ks * BK + c, Ah + flat);
      }
      // stage B tile (128x64 fp16)
#pragma unroll
      for (int i = 0; i < 4; ++i) {
        const int flat = i * 2048 + t * 8;
        const int r = flat >> 6;
        const int c = flat & 63;
        GLD_LDS16(ih + (size_t)(col0 + r) * D_DIM + ks * BK + c, Bh + flat);
      }
      __syncthreads(); // barrier drains vmcnt before compute
#pragma unroll
      for (int ksub = 0; ksub < 2; ++ksub) {
        half8 af[4], bf[4];
#pragma unroll
        for (int fr = 0; fr < 4; ++fr)
          af[fr] = *reinterpret_cast<const half8*>(
              &Ah[(wr * 64 + fr * 16 + ln) * BK + ksub * 32 + lg * 8]);
#pragma unroll
        for (int fc = 0; fc < 4; ++fc)
          bf[fc] = *reinterpret_cast<const half8*>(
              &Bh[(wc * 64 + fc * 16 + ln) * BK + ksub * 32 + lg * 8]);
#pragma unroll
        for (int fr = 0; fr < 4; ++fr)
#pragma unroll
          for (int fc = 0; fc < 4; ++fc)
            acc[fr][fc] = __builtin_amdgcn_mfma_f32_16x16x32_f16(
                af[fr], bf[fc], acc[fr][fc], 0, 0, 0);
      }
    }
    // fold this col-tile into the per-lane running max.
    // C layout (m89-verified, dtype-independent): col = lane&15,
    // row = (lane>>4)*4 + reg.
#pragma unroll
    for (int fr = 0; fr < 4; ++fr)
#pragma unroll
      for (int r = 0; r < 4; ++r)
#pragma unroll
        for (int fc = 0; fc < 4; ++fc) {
          const float v = acc[fr][fc][r];
          const int c = col0 + wc * 64 + fc * 16 + ln;
          if (v > rmax[fr][r]) { // strict >: earliest col wins ties
            rmax[fr][r] = v;
            ridx[fr][r] = c;
          }
        }
  }

  // cross-lane reduce across the 16 col-lanes (xor 1,2,4,8 stays in group)
#pragma unroll
  for (int fr = 0; fr < 4; ++fr)
#pragma unroll
    for (int r = 0; r < 4; ++r) {
      float v = rmax[fr][r];
      int c = ridx[fr][r];
#pragma unroll
      for (int m = 1; m < 16; m <<= 1) {
        const float ov = __shfl_xor(v, m, 64);
        const int oc = __shfl_xor(c, m, 64);
        if (ov > v || (ov == v && oc < c)) {
          v = ov;
          c = oc;
        }
      }
      if (ln == 0) {
        const int rib = wr * 64 + fr * 16 + lg * 4 + r;
        sVal[wc][rib] = v;
        sIdx[wc][rib] = c;
      }
    }
  __syncthreads();

  // loss phase: exact fp32 from original arrays. wave wv -> rows wv*32..+31
  float lsum = 0.0f;
  for (int rr = 0; rr < 32; ++rr) {
    const int rib = wv * 32 + rr;
    const float v0 = sVal[0][rib], v1 = sVal[1][rib];
    const int i0 = sIdx[0][rib], i1 = sIdx[1][rib];
    const int idx = (v1 > v0 || (v1 == v0 && i1 < i0)) ? i1 : i0;
    const float* qr = qf + (size_t)(row0 + rib) * D_DIM + lane * 8;
    const float* gr = itf + (size_t)idx * D_DIM + lane * 8;
    const float4 a0 = reinterpret_cast<const float4*>(qr)[0];
    const float4 a1 = reinterpret_cast<const float4*>(qr)[1];
    const float4 b0 = reinterpret_cast<const float4*>(gr)[0];
    const float4 b1 = reinterpret_cast<const float4*>(gr)[1];
    const float d0 = a0.x - b0.x, d1 = a0.y - b0.y;
    const float d2 = a0.z - b0.z, d3 = a0.w - b0.w;
    const float d4 = a1.x - b1.x, d5 = a1.y - b1.y;
    const float d6 = a1.z - b1.z, d7 = a1.w - b1.w;
    lsum += d0 * d0 + d1 * d1 + d2 * d2 + d3 * d3 + d4 * d4 + d5 * d5 +
            d6 * d6 + d7 * d7;
  }
#pragma unroll
  for (int m = 1; m < 64; m <<= 1) lsum += __shfl_xor(lsum, m, 64);
  if (lane == 0) sSum[wv] = lsum;
  __syncthreads();
  if (t == 0) partials[blockIdx.x] = sSum[0] + sSum[1] + sSum[2] + sSum[3];
}

__global__ __launch_bounds__(256) void final_reduce(
    const float* __restrict__ partials, float* __restrict__ out) {
  __shared__ float sS[4];
  const int t = threadIdx.x;
  float v = partials[t]; // exactly 256 partials
#pragma unroll
  for (int m = 1; m < 64; m <<= 1) v += __shfl_xor(v, m, 64);
  if ((t & 63) == 0) sS[t >> 6] = v;
  __syncthreads();
  if (t == 0)
    out[0] = (sS[0] + sS[1] + sS[2] + sS[3]) *
             (1.0f / ((float)N_ROWS * (float)D_DIM));
}

extern "C" void kernel_launch(void* const* d_in, const int* in_sizes, int n_in,
                              void* d_out, int out_size, void* d_ws,
                              size_t ws_size, hipStream_t stream) {
  const float* qf = (const float*)d_in[0];  // [32768][512]
  const float* itf = (const float*)d_in[1]; // [4096][512]
  _Float16* qh = (_Float16*)d_ws;
  _Float16* ih = (_Float16*)((char*)d_ws + (size_t)N_ROWS * D_DIM * 2);
  float* partials = (float*)((char*)d_ws + (size_t)N_ROWS * D_DIM * 2 +
                             (size_t)M_ITEMS * D_DIM * 2);
  float* out = (float*)d_out;

  cast_f32_f16<<<2048, 256, 0, stream>>>(qf, qh, N_ROWS * D_DIM / 4);
  cast_f32_f16<<<512, 256, 0, stream>>>(itf, ih, M_ITEMS * D_DIM / 4);
  gather_loss_main<<<N_ROWS / BM, 256, 0, stream>>>(qf, itf, qh, ih, partials);
  final_reduce<<<1, 256, 0, stream>>>(partials, out);
}

// Round 2
// 278.189 us; speedup vs baseline: 1.3262x; 1.3262x over previous
//
#include <hip/hip_runtime.h>
#include <hip/hip_bf16.h>
#include <stdint.h>

// GatheringLoss: score = q[32768x512] @ items[4096x512]^T, idx = argmax_row,
// out = mean((q - items[idx])^2).
// R2: col-split x4 for occupancy (grid 1024 -> 4 blocks/CU; R1 had 1 block/CU,
// Occupancy 12%). Per-split (max,idx) -> ws; merge_loss kernel does the
// split-merge + exact fp32 MSE.
//
// ws layout: [0,32MB) q_fp16 | [+4MB) items_fp16 | [+512KB) val[4][32768] f32
//            | [+512KB) idx[4][32768] i32 | [+1KB) partials[256]

#define D_DIM 512
#define M_ITEMS 4096
#define N_ROWS 32768
#define BM 128
#define BN 128
#define BK 64
#define N_CT (M_ITEMS / BN) // 32
#define N_KS (D_DIM / BK)   // 8
#define NSPLIT 4
#define CT_PER (N_CT / NSPLIT) // 8

typedef _Float16 half8 __attribute__((ext_vector_type(8)));
typedef _Float16 half4h __attribute__((ext_vector_type(4)));
typedef float f32x4 __attribute__((ext_vector_type(4)));

#define GLD_LDS16(g, l)                                                        \
  __builtin_amdgcn_global_load_lds(                                            \
      (__attribute__((address_space(1))) const void*)(g),                      \
      (__attribute__((address_space(3))) void*)(l), 16, 0, 0)

__global__ __launch_bounds__(256) void cast_f32_f16(
    const float* __restrict__ in, _Float16* __restrict__ out, int n4) {
  const int stride = gridDim.x * blockDim.x;
  for (int i = blockIdx.x * blockDim.x + threadIdx.x; i < n4; i += stride) {
    const float4 v = reinterpret_cast<const float4*>(in)[i];
    half4h h;
    h.x = (_Float16)v.x;
    h.y = (_Float16)v.y;
    h.z = (_Float16)v.z;
    h.w = (_Float16)v.w;
    reinterpret_cast<half4h*>(out)[i] = h;
  }
}

__global__ __launch_bounds__(256) void score_argmax(
    const _Float16* __restrict__ qh, const _Float16* __restrict__ ih,
    float* __restrict__ valArr, int* __restrict__ idxArr) {
  __shared__ _Float16 Ah[BM * BK]; // [row][k] linear (global_load_lds dest)
  __shared__ _Float16 Bh[BN * BK]; // [col][k] linear
  __shared__ float sVal[2][BM];
  __shared__ int sIdx[2][BM];

  const int t = threadIdx.x;
  const int lane = t & 63;
  const int wv = t >> 6;  // 0..3
  const int wr = wv >> 1; // row half 0..1
  const int wc = wv & 1;  // col half 0..1
  const int ln = lane & 15;
  const int lg = lane >> 4; // 0..3
  const int bid = blockIdx.x;
  const int rb = bid >> 2;         // row-block 0..255 (consecutive bids share A)
  const int split = bid & 3;       // col-split 0..3
  const int row0 = rb * BM;

  float rmax[4][4];
  int ridx[4][4];
#pragma unroll
  for (int a = 0; a < 4; ++a)
#pragma unroll
    for (int b = 0; b < 4; ++b) {
      rmax[a][b] = -3.0e38f;
      ridx[a][b] = 0;
    }

  for (int ctl = 0; ctl < CT_PER; ++ctl) {
    const int ct = split * CT_PER + ctl;
    const int col0 = ct * BN;
    f32x4 acc[4][4];
#pragma unroll
    for (int a = 0; a < 4; ++a)
#pragma unroll
      for (int b = 0; b < 4; ++b)
#pragma unroll
        for (int r = 0; r < 4; ++r) acc[a][b][r] = 0.0f;

    for (int ks = 0; ks < N_KS; ++ks) {
      __syncthreads(); // protect LDS from previous readers
#pragma unroll
      for (int i = 0; i < 4; ++i) {
        const int flat = i * 2048 + t * 8;
        const int r = flat >> 6;
        const int c = flat & 63;
        GLD_LDS16(qh + (size_t)(row0 + r) * D_DIM + ks * BK + c, Ah + flat);
      }
#pragma unroll
      for (int i = 0; i < 4; ++i) {
        const int flat = i * 2048 + t * 8;
        const int r = flat >> 6;
        const int c = flat & 63;
        GLD_LDS16(ih + (size_t)(col0 + r) * D_DIM + ks * BK + c, Bh + flat);
      }
      __syncthreads(); // barrier drains vmcnt before compute
#pragma unroll
      for (int ksub = 0; ksub < 2; ++ksub) {
        half8 af[4], bf[4];
#pragma unroll
        for (int fr = 0; fr < 4; ++fr)
          af[fr] = *reinterpret_cast<const half8*>(
              &Ah[(wr * 64 + fr * 16 + ln) * BK + ksub * 32 + lg * 8]);
#pragma unroll
        for (int fc = 0; fc < 4; ++fc)
          bf[fc] = *reinterpret_cast<const half8*>(
              &Bh[(wc * 64 + fc * 16 + ln) * BK + ksub * 32 + lg * 8]);
#pragma unroll
        for (int fr = 0; fr < 4; ++fr)
#pragma unroll
          for (int fc = 0; fc < 4; ++fc)
            acc[fr][fc] = __builtin_amdgcn_mfma_f32_16x16x32_f16(
                af[fr], bf[fc], acc[fr][fc], 0, 0, 0);
      }
    }
    // fold col-tile into running (max,idx). C layout: col=lane&15,
    // row=(lane>>4)*4+reg (m89-verified, dtype-independent).
#pragma unroll
    for (int fr = 0; fr < 4; ++fr)
#pragma unroll
      for (int r = 0; r < 4; ++r)
#pragma unroll
        for (int fc = 0; fc < 4; ++fc) {
          const float v = acc[fr][fc][r];
          const int c = col0 + wc * 64 + fc * 16 + ln;
          if (v > rmax[fr][r]) { // strict >: earliest col wins ties
            rmax[fr][r] = v;
            ridx[fr][r] = c;
          }
        }
  }

  // cross-lane reduce across the 16 col-lanes
#pragma unroll
  for (int fr = 0; fr < 4; ++fr)
#pragma unroll
    for (int r = 0; r < 4; ++r) {
      float v = rmax[fr][r];
      int c = ridx[fr][r];
#pragma unroll
      for (int m = 1; m < 16; m <<= 1) {
        const float ov = __shfl_xor(v, m, 64);
        const int oc = __shfl_xor(c, m, 64);
        if (ov > v || (ov == v && oc < c)) {
          v = ov;
          c = oc;
        }
      }
      if (ln == 0) {
        const int rib = wr * 64 + fr * 16 + lg * 4 + r;
        sVal[wc][rib] = v;
        sIdx[wc][rib] = c;
      }
    }
  __syncthreads();

  if (t < BM) {
    const float v0 = sVal[0][t], v1 = sVal[1][t];
    const int i0 = sIdx[0][t], i1 = sIdx[1][t];
    const bool take1 = (v1 > v0) || (v1 == v0 && i1 < i0);
    valArr[(size_t)split * N_ROWS + row0 + t] = take1 ? v1 : v0;
    idxArr[(size_t)split * N_ROWS + row0 + t] = take1 ? i1 : i0;
  }
}

__global__ __launch_bounds__(256) void merge_loss(
    const float* __restrict__ qf, const float* __restrict__ itf,
    const float* __restrict__ valArr, const int* __restrict__ idxArr,
    float* __restrict__ partials) {
  __shared__ float sSum[4];
  const int t = threadIdx.x;
  const int lane = t & 63;
  const int wv = t >> 6;
  const int row0 = blockIdx.x * BM;

  float lsum = 0.0f;
  for (int rr = 0; rr < 32; ++rr) {
    const int row = row0 + wv * 32 + rr;
    // merge 4 splits (broadcast loads, L2-resident)
    float bv = valArr[row];
    int bi = idxArr[row];
#pragma unroll
    for (int s = 1; s < NSPLIT; ++s) {
      const float v = valArr[(size_t)s * N_ROWS + row];
      const int ii = idxArr[(size_t)s * N_ROWS + row];
      if (v > bv || (v == bv && ii < bi)) {
        bv = v;
        bi = ii;
      }
    }
    const float* qr = qf + (size_t)row * D_DIM + lane * 8;
    const float* gr = itf + (size_t)bi * D_DIM + lane * 8;
    const float4 a0 = reinterpret_cast<const float4*>(qr)[0];
    const float4 a1 = reinterpret_cast<const float4*>(qr)[1];
    const float4 b0 = reinterpret_cast<const float4*>(gr)[0];
    const float4 b1 = reinterpret_cast<const float4*>(gr)[1];
    const float d0 = a0.x - b0.x, d1 = a0.y - b0.y;
    const float d2 = a0.z - b0.z, d3 = a0.w - b0.w;
    const float d4 = a1.x - b1.x, d5 = a1.y - b1.y;
    const float d6 = a1.z - b1.z, d7 = a1.w - b1.w;
    lsum += d0 * d0 + d1 * d1 + d2 * d2 + d3 * d3 + d4 * d4 + d5 * d5 +
            d6 * d6 + d7 * d7;
  }
#pragma unroll
  for (int m = 1; m < 64; m <<= 1) lsum += __shfl_xor(lsum, m, 64);
  if (lane == 0) sSum[wv] = lsum;
  __syncthreads();
  if (t == 0) partials[blockIdx.x] = sSum[0] + sSum[1] + sSum[2] + sSum[3];
}

__global__ __launch_bounds__(256) void final_reduce(
    const float* __restrict__ partials, float* __restrict__ out) {
  __shared__ float sS[4];
  const int t = threadIdx.x;
  float v = partials[t]; // exactly 256 partials
#pragma unroll
  for (int m = 1; m < 64; m <<= 1) v += __shfl_xor(v, m, 64);
  if ((t & 63) == 0) sS[t >> 6] = v;
  __syncthreads();
  if (t == 0)
    out[0] = (sS[0] + sS[1] + sS[2] + sS[3]) *
             (1.0f / ((float)N_ROWS * (float)D_DIM));
}

extern "C" void kernel_launch(void* const* d_in, const int* in_sizes, int n_in,
                              void* d_out, int out_size, void* d_ws,
                              size_t ws_size, hipStream_t stream) {
  const float* qf = (const float*)d_in[0];  // [32768][512]
  const float* itf = (const float*)d_in[1]; // [4096][512]
  char* ws = (char*)d_ws;
  _Float16* qh = (_Float16*)ws;                                   // 32 MB
  _Float16* ih = (_Float16*)(ws + (size_t)N_ROWS * D_DIM * 2);    // 4 MB
  char* p = ws + (size_t)N_ROWS * D_DIM * 2 + (size_t)M_ITEMS * D_DIM * 2;
  float* valArr = (float*)p;                                      // 512 KB
  int* idxArr = (int*)(p + (size_t)NSPLIT * N_ROWS * 4);          // 512 KB
  float* partials = (float*)(p + (size_t)2 * NSPLIT * N_ROWS * 4); // 1 KB
  float* out = (float*)d_out;

  cast_f32_f16<<<2048, 256, 0, stream>>>(qf, qh, N_ROWS * D_DIM / 4);
  cast_f32_f16<<<512, 256, 0, stream>>>(itf, ih, M_ITEMS * D_DIM / 4);
  score_argmax<<<N_ROWS / BM * NSPLIT, 256, 0, stream>>>(qh, ih, valArr,
                                                         idxArr);
  merge_loss<<<N_ROWS / BM, 256, 0, stream>>>(qf, itf, valArr, idxArr,
                                              partials);
  final_reduce<<<1, 256, 0, stream>>>(partials, out);
}